// Round 16
// baseline (3271.246 us; speedup 1.0000x reference)
//
#include <hip/hip_runtime.h>
#include <hip/hip_bf16.h>
#include <math.h>

#define BB 16
#define NN 1024
#define CC 16
#define DD 64
#define TT 32

typedef __bf16 bf16;
typedef __bf16 bf16x8 __attribute__((ext_vector_type(8)));
typedef __bf16 bf16x4 __attribute__((ext_vector_type(4)));
typedef float f32x4 __attribute__((ext_vector_type(4)));
typedef unsigned int u32;
typedef unsigned long long u64;
typedef u32 u32v4 __attribute__((ext_vector_type(4)));

__device__ __forceinline__ void split2(float x, bf16& h, bf16& l) {
    h = (bf16)x;
    l = (bf16)(x - (float)h);
}

__device__ __forceinline__ float fast_tanh(float x) {
    float ax = fabsf(x);
    float e = __expf(-2.f * ax);
    float t = 1.f - 2.f * e / (1.f + e);
    return copysignf(t, x);
}

// 8 adjacency bits -> bf16 {0.0,1.0} x8 (self-loop added in phase 2 as +vh).
__device__ __forceinline__ bf16x8 expand_bits(u32 b8) {
    u32 w[4];
    #pragma unroll
    for (int p = 0; p < 4; ++p) {
        u32 tt = b8 >> (2 * p);
        w[p] = ((tt & 1u) | ((tt & 2u) << 15)) * 0x3F80u;
    }
    u32v4 u = { w[0], w[1], w[2], w[3] };
    return __builtin_bit_cast(bf16x8, u);
}

// Vfrag layout: [b][ks=node>>5][j=d][khi=(node>>3)&3][e=node&7], bf16.

// ---------------- prep: pack Mvv bits, Vf[0] init, weight transposes ----------------
__global__ __launch_bounds__(256) void prep_kernel(
    const float* __restrict__ Mvv, const float* __restrict__ v_init,
    const float* __restrict__ W_v, const float* __restrict__ W_vv,
    u64* __restrict__ Abits,
    bf16* __restrict__ VfHi, bf16* __restrict__ VfLo,
    bf16* __restrict__ WvTh, bf16* __restrict__ WvTl,
    bf16* __restrict__ WvvTh, bf16* __restrict__ WvvTl)
{
    int gid = blockIdx.x, tid = threadIdx.x;
    if (gid < 4096) {
        int w = tid >> 6, lane = tid & 63;
        for (int it = 0; it < 16; ++it) {
            int W = gid * 64 + w * 16 + it;      // [0, 262144)
            int bb  = W >> 14;
            int row = (W >> 4) & 1023;
            int wq  = W & 15;
            float x = Mvv[(((size_t)bb << 10) + row) * 1024 + wq * 64 + lane];
            u64 m = __ballot(x != 0.0f);
            if (lane == 0) Abits[W] = m;
        }
    } else if (gid < 4608) {
        size_t idx = ((size_t)(gid - 4096) * 256 + tid) * 8;   // over Vfrag flat (B*64K)
        int j = (int)((idx >> 5) & 63);
        bf16 h, l; split2(v_init[j], h, l);
        bf16x8 oh, ol;
        #pragma unroll
        for (int e = 0; e < 8; ++e) { oh[e] = h; ol[e] = l; }
        *(bf16x8*)(VfHi + idx) = oh;
        *(bf16x8*)(VfLo + idx) = ol;
    } else {
        for (int e = tid; e < DD * DD; e += 256) {
            int n = e >> 6, k = e & 63;
            bf16 h, l;
            split2(W_v[k * DD + n], h, l);   // WvT[n][k] = W_v[k][n]
            WvTh[e] = h; WvTl[e] = l;
            split2(W_vv[k * DD + n], h, l);
            WvvTh[e] = h; WvvTl[e] = l;
        }
    }
}

// ---------------- persistent kernel: 256 blocks x 512 threads, all 32 steps + vote ----------------
// Per-batch barrier over the 16 blocks of batch b (monotonic counter, device scope).
// Co-residency guaranteed: grid=256 <= 256 CUs x capacity (launch_bounds(512,2), LDS 76KB -> 2 blocks/CU).
__global__ __launch_bounds__(512, 2) void mega_kernel(
    const u64* __restrict__ Abits,
    bf16* __restrict__ VfH0, bf16* __restrict__ VfL0,
    bf16* __restrict__ VfH1, bf16* __restrict__ VfL1,
    float* __restrict__ pb0, float* __restrict__ pb1, u32* __restrict__ ctr,
    const int* __restrict__ n_colors, const float* __restrict__ ch0,
    const float* __restrict__ Wc, const float* __restrict__ Wcv, const float* __restrict__ bc,
    const float* __restrict__ Wvc, const float* __restrict__ bv,
    const bf16* __restrict__ WvTh, const bf16* __restrict__ WvTl,
    const bf16* __restrict__ WvvTh, const bf16* __restrict__ WvvTl,
    const float* __restrict__ v_init,
    const float* __restrict__ W1, const float* __restrict__ b1, const float* __restrict__ W2,
    float* __restrict__ partial)
{
    __shared__ float sWc[4096];                 // 16 KB, staged once
    __shared__ float sChI[1024];                // persistent ch state
    __shared__ float sRed[512];
    __shared__ float sBc[64], sBv[64], sVs[64], sMv[64], sCs[64], sCv[64];
    __shared__ float vagg[2][64 * 65];          // 33.3 KB
    __shared__ bf16 sVhH[64 * 72], sVhL[64 * 72]; // persistent vh rows, 18.4 KB

    int tid  = threadIdx.x;
    int b    = blockIdx.x & 15;
    int blkr = blockIdx.x >> 4;
    int m0   = blkr * 64;
    int ncol = n_colors[b];
    int d = tid & 63, q = tid >> 6;

    int lane = tid & 63, w = tid >> 6;
    int l16 = lane & 15, lhi = lane >> 4;
    int wm = w & 1, wn = (w >> 1) & 1, wk = w >> 2;
    int rt = (w & 3) * 16, ct = (w >> 2) * 32;

    // ---- one-time staging ----
    for (int e = tid; e < 4096; e += 512) sWc[e] = Wc[e];
    for (int e = tid; e < 1024; e += 512) sChI[e] = ch0[(size_t)b * 1024 + e];
    if (tid < 64) { sBc[tid] = bc[tid]; sBv[tid] = bv[tid]; }
    for (int e = tid; e < 4096; e += 512) {
        int row = e >> 6, col = e & 63;
        bf16 h, l; split2(v_init[col], h, l);
        sVhH[row * 72 + col] = h;
        sVhL[row * 72 + col] = l;
    }
    __syncthreads();

    const u64* Ab = Abits + ((size_t)b * NN + m0 + wm * 32 + l16) * 16 + wk * 8;

    #pragma unroll 1
    for (int t = 0; t < TT; ++t) {
        const bf16* VfH = ((t & 1) ? VfH1 : VfH0) + (size_t)b * 65536;
        const bf16* VfL = ((t & 1) ? VfL1 : VfL0) + (size_t)b * 65536;
        bf16* VfHn = (t & 1) ? VfH0 : VfH1;
        bf16* VfLn = (t & 1) ? VfL0 : VfL1;
        const float* part_prev = (t & 1) ? pb0 : pb1;   // pb[(t+1)&1]
        float* part_out = (t & 1) ? pb1 : pb0;          // pb[t&1]

        float pr[8];
        if (t > 0) {
            #pragma unroll
            for (int j = 0; j < 8; ++j)
                pr[j] = part_prev[(size_t)b * 4096 + (q * 8 + j) * 64 + d];
        }

        // ---- phase 1: v_agg(partial) = bits @ (vh_hi + vh_lo) ----
        f32x4 acc[2][2];
        #pragma unroll
        for (int mi = 0; mi < 2; ++mi)
            #pragma unroll
            for (int nt = 0; nt < 2; ++nt) acc[mi][nt] = (f32x4){0.f, 0.f, 0.f, 0.f};

        #pragma unroll
        for (int kt = 0; kt < 4; ++kt) {
            u32v4 aw0 = *(const u32v4*)(Ab + kt * 2);
            u32v4 aw1 = *(const u32v4*)(Ab + 256 + kt * 2);
            #pragma unroll
            for (int kk = 0; kk < 4; ++kk) {
                int ks = wk * 16 + kt * 4 + kk;
                bf16x8 a0 = expand_bits((aw0[kk] >> (lhi * 8)) & 0xFFu);
                bf16x8 a1 = expand_bits((aw1[kk] >> (lhi * 8)) & 0xFFu);
                size_t fo = (size_t)ks * 2048 + (wn * 32 + l16) * 32 + lhi * 8;
                bf16x8 bh0 = *(const bf16x8*)(VfH + fo);
                bf16x8 bl0 = *(const bf16x8*)(VfL + fo);
                bf16x8 bh1 = *(const bf16x8*)(VfH + fo + 512);
                bf16x8 bl1 = *(const bf16x8*)(VfL + fo + 512);
                acc[0][0] = __builtin_amdgcn_mfma_f32_16x16x32_bf16(a0, bh0, acc[0][0], 0, 0, 0);
                acc[0][1] = __builtin_amdgcn_mfma_f32_16x16x32_bf16(a0, bh1, acc[0][1], 0, 0, 0);
                acc[1][0] = __builtin_amdgcn_mfma_f32_16x16x32_bf16(a1, bh0, acc[1][0], 0, 0, 0);
                acc[1][1] = __builtin_amdgcn_mfma_f32_16x16x32_bf16(a1, bh1, acc[1][1], 0, 0, 0);
                acc[0][0] = __builtin_amdgcn_mfma_f32_16x16x32_bf16(a0, bl0, acc[0][0], 0, 0, 0);
                acc[0][1] = __builtin_amdgcn_mfma_f32_16x16x32_bf16(a0, bl1, acc[0][1], 0, 0, 0);
                acc[1][0] = __builtin_amdgcn_mfma_f32_16x16x32_bf16(a1, bl0, acc[1][0], 0, 0, 0);
                acc[1][1] = __builtin_amdgcn_mfma_f32_16x16x32_bf16(a1, bl1, acc[1][1], 0, 0, 0);
            }
        }

        // ---- hoisted phase-2a: p2 = vh@W_v (vh from LDS) ----
        f32x4 p2[2][2];
        #pragma unroll
        for (int nt = 0; nt < 2; ++nt)
            #pragma unroll
            for (int kk = 0; kk < 2; ++kk) p2[nt][kk] = (f32x4){0.f, 0.f, 0.f, 0.f};

        bf16x8 a1h[2], a1l[2];
        #pragma unroll
        for (int kk = 0; kk < 2; ++kk) {
            int d0 = kk * 32 + lhi * 8;
            int vl = (rt + l16) * 72 + d0;
            a1h[kk] = *(const bf16x8*)(&sVhH[vl]);
            a1l[kk] = *(const bf16x8*)(&sVhL[vl]);
            #pragma unroll
            for (int nt = 0; nt < 2; ++nt) {
                int woff = (ct + nt * 16 + l16) * 64 + d0;
                bf16x8 b1h = *(const bf16x8*)(WvTh + woff);
                bf16x8 b1l = *(const bf16x8*)(WvTl + woff);
                p2[nt][kk] = __builtin_amdgcn_mfma_f32_16x16x32_bf16(a1h[kk], b1h, p2[nt][kk], 0, 0, 0);
                p2[nt][kk] = __builtin_amdgcn_mfma_f32_16x16x32_bf16(a1l[kk], b1h, p2[nt][kk], 0, 0, 0);
                p2[nt][kk] = __builtin_amdgcn_mfma_f32_16x16x32_bf16(a1h[kk], b1l, p2[nt][kk], 0, 0, 0);
            }
        }

        // partial acc -> LDS (per K-half)
        #pragma unroll
        for (int mi = 0; mi < 2; ++mi)
            #pragma unroll
            for (int nt = 0; nt < 2; ++nt)
                #pragma unroll
                for (int r = 0; r < 4; ++r)
                    vagg[wk][(wm * 32 + mi * 16 + lhi * 4 + r) * 65 + wn * 32 + nt * 16 + l16] = acc[mi][nt][r];
        __syncthreads();

        // ---- phase 0: color-state update (persistent sChI) ----
        if (t > 0) {
            {
                float s = 0.f;
                #pragma unroll
                for (int j = 0; j < 8; ++j) s += pr[j];
                sRed[tid] = s;
            }
            __syncthreads();
            if (tid < 64) {
                float v = 0.f;
                #pragma unroll
                for (int i = 0; i < 8; ++i) v += sRed[tid + 64 * i];
                sVs[tid] = v;
            }
            __syncthreads();
            {
                float pm = 0.f;
                #pragma unroll
                for (int j = 0; j < 8; ++j) { int k = q * 8 + j; pm += sVs[k] * Wcv[k * 64 + d]; }
                sRed[tid] = pm;
            }
            __syncthreads();
            if (tid < 64) {
                float v = 0.f;
                #pragma unroll
                for (int i = 0; i < 8; ++i) v += sRed[tid + 64 * i];
                sMv[tid] = v;
            }
            __syncthreads();
            float cn[2];
            #pragma unroll
            for (int ci = 0; ci < 2; ++ci) {
                int c = q * 2 + ci;
                float s = sBc[d] + ((c < ncol) ? sMv[d] : 0.f);
                for (int k = 0; k < 64; ++k) s += sChI[c * 64 + k] * sWc[k * 64 + d];
                cn[ci] = fast_tanh(s);
            }
            __syncthreads();
            #pragma unroll
            for (int ci = 0; ci < 2; ++ci) sChI[(q * 2 + ci) * 64 + d] = cn[ci];
            __syncthreads();
        }
        {
            float pcs = 0.f;
            #pragma unroll
            for (int ci = 0; ci < 2; ++ci) { int c = q * 2 + ci; if (c < ncol) pcs += sChI[c * 64 + d]; }
            sRed[tid] = pcs;
        }
        __syncthreads();
        if (tid < 64) {
            float v = 0.f;
            #pragma unroll
            for (int i = 0; i < 8; ++i) v += sRed[tid + 64 * i];
            sCs[tid] = v;
        }
        __syncthreads();
        {
            float pv = 0.f;
            #pragma unroll
            for (int j = 0; j < 8; ++j) { int k = q * 8 + j; pv += sCs[k] * Wvc[k * 64 + d]; }
            sRed[tid] = pv;
        }
        __syncthreads();
        if (tid < 64) {
            float v = sBv[tid];
            #pragma unroll
            for (int i = 0; i < 8; ++i) v += sRed[tid + 64 * i];
            sCv[tid] = v;
        }
        __syncthreads();

        // ---- phase 2b: p2 += (v_agg + vh)@W_vv ; + cvec ; tanh ----
        #pragma unroll
        for (int kk = 0; kk < 2; ++kk) {
            int d0 = kk * 32 + lhi * 8;
            int vb = (rt + l16) * 65 + d0;
            bf16x8 a2h, a2l;
            #pragma unroll
            for (int e = 0; e < 8; ++e) {
                float v = vagg[0][vb + e] + vagg[1][vb + e] + (float)a1h[kk][e] + (float)a1l[kk][e];
                bf16 h, l; split2(v, h, l);
                a2h[e] = h; a2l[e] = l;
            }
            #pragma unroll
            for (int nt = 0; nt < 2; ++nt) {
                int woff = (ct + nt * 16 + l16) * 64 + d0;
                bf16x8 b2h = *(const bf16x8*)(WvvTh + woff);
                bf16x8 b2l = *(const bf16x8*)(WvvTl + woff);
                p2[nt][kk] = __builtin_amdgcn_mfma_f32_16x16x32_bf16(a2h, b2h, p2[nt][kk], 0, 0, 0);
                p2[nt][kk] = __builtin_amdgcn_mfma_f32_16x16x32_bf16(a2l, b2h, p2[nt][kk], 0, 0, 0);
                p2[nt][kk] = __builtin_amdgcn_mfma_f32_16x16x32_bf16(a2h, b2l, p2[nt][kk], 0, 0, 0);
            }
        }

        float tvv[2][4];
        #pragma unroll
        for (int nt = 0; nt < 2; ++nt) {
            float cv = sCv[ct + nt * 16 + l16];
            #pragma unroll
            for (int r = 0; r < 4; ++r) tvv[nt][r] = fast_tanh(p2[nt][0][r] + p2[nt][1][r] + cv);
        }

        if (t < TT - 1) {
            int ksW = (m0 + rt) >> 5;
            int khi = 2 * ((rt >> 4) & 1) + (lhi >> 1);
            #pragma unroll
            for (int nt = 0; nt < 2; ++nt) {
                int col = ct + nt * 16 + l16;
                float cs = tvv[nt][0] + tvv[nt][1] + tvv[nt][2] + tvv[nt][3];
                cs += __shfl_xor(cs, 16);
                cs += __shfl_xor(cs, 32);
                if (lhi == 0)
                    part_out[(((size_t)b * 16 + blkr) * 4 + (w & 3)) * 64 + col] = cs;

                bf16x4 pkh, pkl;
                #pragma unroll
                for (int r = 0; r < 4; ++r) {
                    bf16 h, l; split2(tvv[nt][r], h, l);
                    pkh[r] = h; pkl[r] = l;
                    int row = rt + lhi * 4 + r;
                    sVhH[row * 72 + col] = h;      // safe: all phase-2a reads done (vagg barrier)
                    sVhL[row * 72 + col] = l;
                }
                size_t fo = (size_t)b * 65536 + (size_t)ksW * 2048 + col * 32 + khi * 8 + (lhi & 1) * 4;
                *(bf16x4*)(VfHn + fo) = pkh;
                *(bf16x4*)(VfLn + fo) = pkl;
            }

            // ---- per-batch barrier over 16 blocks ----
            __threadfence();
            __syncthreads();
            if (tid == 0) {
                __hip_atomic_fetch_add(&ctr[b], 1u, __ATOMIC_RELEASE, __HIP_MEMORY_SCOPE_AGENT);
                u32 target = 16u * (u32)(t + 1);
                int spins = 0;
                while (__hip_atomic_load(&ctr[b], __ATOMIC_ACQUIRE, __HIP_MEMORY_SCOPE_AGENT) < target
                       && spins < 2000000) {
                    ++spins;
                    __builtin_amdgcn_s_sleep(2);
                }
                __threadfence();
            }
            __syncthreads();
        } else {
            // ---- fused vote MLP over this block's 64 rows ----
            __syncthreads();   // all vagg reads in phase 2b complete
            float* sX  = &vagg[0][0];     // [64][65] fp32 vh rows
            float* sW1 = &vagg[1][0];     // 1024 fp32
            #pragma unroll
            for (int nt = 0; nt < 2; ++nt) {
                int col = ct + nt * 16 + l16;
                #pragma unroll
                for (int r = 0; r < 4; ++r)
                    sX[(rt + lhi * 4 + r) * 65 + col] = tvv[nt][r];
            }
            for (int e = tid; e < 1024; e += 512) sW1[e] = W1[e];
            if (tid < 16) { sVs[tid] = W2[tid]; sMv[tid] = b1[tid]; }
            __syncthreads();

            int nl = tid & 63;
            int jq = tid >> 6;
            float h0 = sMv[jq * 2], h1 = sMv[jq * 2 + 1];
            for (int dd = 0; dd < 64; ++dd) {
                float x = sX[nl * 65 + dd];
                h0 += x * sW1[dd * 16 + jq * 2];
                h1 += x * sW1[dd * 16 + jq * 2 + 1];
            }
            float pv = sVs[jq * 2] / (1.f + __expf(-h0)) + sVs[jq * 2 + 1] / (1.f + __expf(-h1));
            sRed[tid] = pv;
            __syncthreads();
            if (tid < 64) {
                float v = 0.f;
                #pragma unroll
                for (int i = 0; i < 8; ++i) v += sRed[tid + 64 * i];
                #pragma unroll
                for (int off = 1; off < 64; off <<= 1) v += __shfl_xor(v, off);
                if (tid == 0) partial[blockIdx.x] = v;
            }
        }
    }
}

// ---------------- final reduce: 16 partials per batch, mean+sigmoid ----------------
__global__ __launch_bounds__(256) void final_reduce_kernel(
    const float* __restrict__ partial, const float* __restrict__ b2, float* __restrict__ out)
{
    int tid = threadIdx.x;
    int b = tid >> 4, p = tid & 15;
    float v = partial[p * 16 + b];
    #pragma unroll
    for (int off = 1; off < 16; off <<= 1) v += __shfl_xor(v, off);
    if (p == 0) out[b] = 1.f / (1.f + expf(-(v / 1024.f + b2[0])));
}

extern "C" void kernel_launch(void* const* d_in, const int* in_sizes, int n_in,
                              void* d_out, int out_size, void* d_ws, size_t ws_size,
                              hipStream_t stream) {
    const float* Mvv  = (const float*)d_in[0];
    const int*   ncol = (const int*)d_in[1];
    const float* vini = (const float*)d_in[2];
    const float* ch0  = (const float*)d_in[3];
    const float* W_v  = (const float*)d_in[4];
    const float* W_vv = (const float*)d_in[5];
    const float* W_vc = (const float*)d_in[6];
    const float* b_v  = (const float*)d_in[7];
    const float* W_c  = (const float*)d_in[8];
    const float* W_cv = (const float*)d_in[9];
    const float* b_c  = (const float*)d_in[10];
    const float* W1   = (const float*)d_in[11];
    const float* b1   = (const float*)d_in[12];
    const float* W2   = (const float*)d_in[13];
    const float* b2   = (const float*)d_in[14];

    char* base = (char*)d_ws;
    size_t off = 0;
    u64* Abits = (u64*)(base + off); off += (size_t)BB * NN * 16 * 8;        // 2 MB
    const size_t SVH = (size_t)BB * NN * DD * 2;                              // 2 MB
    bf16* VfH0 = (bf16*)(base + off); off += SVH;
    bf16* VfL0 = (bf16*)(base + off); off += SVH;
    bf16* VfH1 = (bf16*)(base + off); off += SVH;
    bf16* VfL1 = (bf16*)(base + off); off += SVH;
    const size_t SPB = (size_t)BB * 64 * DD * 4;                              // 256 KB
    float* pb0 = (float*)(base + off); off += SPB;
    float* pb1 = (float*)(base + off); off += SPB;
    bf16* WvTh  = (bf16*)(base + off); off += DD * DD * 2;
    bf16* WvTl  = (bf16*)(base + off); off += DD * DD * 2;
    bf16* WvvTh = (bf16*)(base + off); off += DD * DD * 2;
    bf16* WvvTl = (bf16*)(base + off); off += DD * DD * 2;
    float* partial = (float*)(base + off); off += 256 * 4;
    u32* ctr = (u32*)(base + off); off += 16 * 4;

    prep_kernel<<<4609, 256, 0, stream>>>(Mvv, vini, W_v, W_vv, Abits,
        VfH0, VfL0, WvTh, WvTl, WvvTh, WvvTl);

    hipMemsetAsync(ctr, 0, 16 * sizeof(u32), stream);

    {
        const u64* a0 = Abits;
        bf16 *p1 = VfH0, *p2 = VfL0, *p3 = VfH1, *p4 = VfL1;
        float *p5 = pb0, *p6 = pb1;
        u32* p7 = ctr;
        const int* p8 = ncol;
        const float *p9 = ch0, *p10 = W_c, *p11 = W_cv, *p12 = b_c, *p13 = W_vc, *p14 = b_v;
        const bf16 *p15 = WvTh, *p16 = WvTl, *p17 = WvvTh, *p18 = WvvTl;
        const float *p19 = vini, *p20 = W1, *p21 = b1, *p22 = W2;
        float* p23 = partial;
        void* args[] = { &a0, &p1, &p2, &p3, &p4, &p5, &p6, &p7, &p8, &p9, &p10, &p11,
                         &p12, &p13, &p14, &p15, &p16, &p17, &p18, &p19, &p20, &p21, &p22, &p23 };
        hipLaunchKernel((const void*)mega_kernel, dim3(256), dim3(512), args, 0, stream);
    }

    final_reduce_kernel<<<1, 256, 0, stream>>>(partial, b2, (float*)d_out);
}

// Round 17
// 698.020 us; speedup vs baseline: 4.6865x; 4.6865x over previous
//
#include <hip/hip_runtime.h>
#include <hip/hip_bf16.h>
#include <math.h>

#define BB 16
#define NN 1024
#define CC 16
#define DD 64
#define TT 32

typedef __bf16 bf16;
typedef __bf16 bf16x8 __attribute__((ext_vector_type(8)));
typedef __bf16 bf16x4 __attribute__((ext_vector_type(4)));
typedef float f32x4 __attribute__((ext_vector_type(4)));
typedef unsigned int u32;
typedef unsigned long long u64;
typedef u32 u32v4 __attribute__((ext_vector_type(4)));

__device__ __forceinline__ void split2(float x, bf16& h, bf16& l) {
    h = (bf16)x;
    l = (bf16)(x - (float)h);
}

__device__ __forceinline__ float fast_tanh(float x) {
    float ax = fabsf(x);
    float e = __expf(-2.f * ax);
    float t = 1.f - 2.f * e / (1.f + e);
    return copysignf(t, x);
}

// 8 adjacency bits -> bf16 {0.0,1.0} x8 (self-loop added in phase 2 as +vh).
__device__ __forceinline__ bf16x8 expand_bits(u32 b8) {
    u32 w[4];
    #pragma unroll
    for (int p = 0; p < 4; ++p) {
        u32 tt = b8 >> (2 * p);
        w[p] = ((tt & 1u) | ((tt & 2u) << 15)) * 0x3F80u;
    }
    u32v4 u = { w[0], w[1], w[2], w[3] };
    return __builtin_bit_cast(bf16x8, u);
}

// Vfrag layout: [b][ks=node>>5][j=d][khi=(node>>3)&3][e=node&7], bf16.

// ---------------- prep ----------------
__global__ __launch_bounds__(256) void prep_kernel(
    const float* __restrict__ Mvv, const float* __restrict__ v_init,
    const float* __restrict__ W_v, const float* __restrict__ W_vv,
    u64* __restrict__ Abits,
    bf16* __restrict__ vhHi, bf16* __restrict__ vhLo,
    bf16* __restrict__ VfHi, bf16* __restrict__ VfLo,
    bf16* __restrict__ WvTh, bf16* __restrict__ WvTl,
    bf16* __restrict__ WvvTh, bf16* __restrict__ WvvTl)
{
    int gid = blockIdx.x, tid = threadIdx.x;
    if (gid < 4096) {
        int w = tid >> 6, lane = tid & 63;
        for (int it = 0; it < 16; ++it) {
            int W = gid * 64 + w * 16 + it;      // [0, 262144)
            int bb  = W >> 14;
            int row = (W >> 4) & 1023;
            int wq  = W & 15;
            float x = Mvv[(((size_t)bb << 10) + row) * 1024 + wq * 64 + lane];
            u64 m = __ballot(x != 0.0f);
            if (lane == 0) Abits[W] = m;
        }
    } else if (gid < 4608) {
        size_t idx = ((size_t)(gid - 4096) * 256 + tid) * 8;   // over B*N*D (row-major vh)
        int d0 = (int)(idx & (DD - 1));
        bf16x8 oh, ol;
        #pragma unroll
        for (int e = 0; e < 8; ++e) { bf16 h, l; split2(v_init[d0 + e], h, l); oh[e] = h; ol[e] = l; }
        *(bf16x8*)(vhHi + idx) = oh;
        *(bf16x8*)(vhLo + idx) = ol;
    } else if (gid < 5120) {
        size_t idx = ((size_t)(gid - 4608) * 256 + tid) * 8;   // over Vfrag flat (B*64K)
        int j = (int)((idx >> 5) & 63);
        bf16 h, l; split2(v_init[j], h, l);
        bf16x8 oh, ol;
        #pragma unroll
        for (int e = 0; e < 8; ++e) { oh[e] = h; ol[e] = l; }
        *(bf16x8*)(VfHi + idx) = oh;
        *(bf16x8*)(VfLo + idx) = ol;
    } else {
        for (int e = tid; e < DD * DD; e += 256) {
            int n = e >> 6, k = e & 63;
            bf16 h, l;
            split2(W_v[k * DD + n], h, l);   // WvT[n][k] = W_v[k][n]
            WvTh[e] = h; WvTl[e] = l;
            split2(W_vv[k * DD + n], h, l);
            WvvTh[e] = h; WvvTl[e] = l;
        }
    }
}

// ---------------- per-step kernel: 256 blocks x 512 threads, 64 rows per block ----------------
__global__ __launch_bounds__(512, 2) void step_kernel(
    const u64* __restrict__ Abits,
    const bf16* __restrict__ vhHi_in, const bf16* __restrict__ vhLo_in,
    const bf16* __restrict__ VfHi_in, const bf16* __restrict__ VfLo_in,
    bf16* __restrict__ vhHi_out, bf16* __restrict__ vhLo_out,
    bf16* __restrict__ VfHi_out, bf16* __restrict__ VfLo_out,
    const float* __restrict__ ch_in, float* __restrict__ ch_out,
    const float* __restrict__ part_prev, float* __restrict__ part_out,
    const int* __restrict__ n_colors,
    const float* __restrict__ Wc, const float* __restrict__ Wcv, const float* __restrict__ bc,
    const float* __restrict__ Wvc, const float* __restrict__ bv,
    const bf16* __restrict__ WvTh, const bf16* __restrict__ WvTl,
    const bf16* __restrict__ WvvTh, const bf16* __restrict__ WvvTl,
    const float* __restrict__ W1, const float* __restrict__ b1, const float* __restrict__ W2,
    float* __restrict__ partial,
    int t)
{
    __shared__ float sWc[4096];
    __shared__ float sChI[1024];
    __shared__ float sRed[512];
    __shared__ float sBc[64], sBv[64], sVs[64], sMv[64], sCs[64], sCv[64];
    __shared__ float vagg[2][64 * 65];

    int tid  = threadIdx.x;
    int b    = blockIdx.x & 15;     // all 16 row-blocks of batch b on same XCD
    int blkr = blockIdx.x >> 4;
    int m0   = blkr * 64;
    int ncol = n_colors[b];
    int d = tid & 63, q = tid >> 6;

    // ---- staging (issued early; latency hides under phase 1) ----
    for (int e = tid; e < 4096; e += 512) sWc[e] = Wc[e];
    for (int e = tid; e < 1024; e += 512) sChI[e] = ch_in[(size_t)b * 1024 + e];
    if (tid < 64) { sBc[tid] = bc[tid]; sBv[tid] = bv[tid]; }

    float pr[8];
    if (t > 0) {
        #pragma unroll
        for (int j = 0; j < 8; ++j)
            pr[j] = part_prev[(size_t)b * 4096 + (q * 8 + j) * 64 + d];
    }

    // ---- phase 1: v_agg(partial) = bits @ (vh_hi + vh_lo); regs/global only ----
    int lane = tid & 63, w = tid >> 6;
    int l16 = lane & 15, lhi = lane >> 4;
    int wm = w & 1, wn = (w >> 1) & 1, wk = w >> 2;

    f32x4 acc[2][2];
    #pragma unroll
    for (int mi = 0; mi < 2; ++mi)
        #pragma unroll
        for (int nt = 0; nt < 2; ++nt) acc[mi][nt] = (f32x4){0.f, 0.f, 0.f, 0.f};

    const u64* Ab = Abits + ((size_t)b * NN + m0 + wm * 32 + l16) * 16 + wk * 8;
    const bf16* VfH = VfHi_in + (size_t)b * 65536;
    const bf16* VfL = VfLo_in + (size_t)b * 65536;

    #pragma unroll
    for (int kt = 0; kt < 4; ++kt) {
        u32v4 aw0 = *(const u32v4*)(Ab + kt * 2);
        u32v4 aw1 = *(const u32v4*)(Ab + 256 + kt * 2);    // mi=1: +16 rows * 16 words
        #pragma unroll
        for (int kk = 0; kk < 4; ++kk) {
            int ks = wk * 16 + kt * 4 + kk;
            bf16x8 a0 = expand_bits((aw0[kk] >> (lhi * 8)) & 0xFFu);
            bf16x8 a1 = expand_bits((aw1[kk] >> (lhi * 8)) & 0xFFu);
            size_t fo = (size_t)ks * 2048 + (wn * 32 + l16) * 32 + lhi * 8;
            bf16x8 bh0 = *(const bf16x8*)(VfH + fo);
            bf16x8 bl0 = *(const bf16x8*)(VfL + fo);
            bf16x8 bh1 = *(const bf16x8*)(VfH + fo + 512); // nt=1: +16 j * 32
            bf16x8 bl1 = *(const bf16x8*)(VfL + fo + 512);
            acc[0][0] = __builtin_amdgcn_mfma_f32_16x16x32_bf16(a0, bh0, acc[0][0], 0, 0, 0);
            acc[0][1] = __builtin_amdgcn_mfma_f32_16x16x32_bf16(a0, bh1, acc[0][1], 0, 0, 0);
            acc[1][0] = __builtin_amdgcn_mfma_f32_16x16x32_bf16(a1, bh0, acc[1][0], 0, 0, 0);
            acc[1][1] = __builtin_amdgcn_mfma_f32_16x16x32_bf16(a1, bh1, acc[1][1], 0, 0, 0);
            acc[0][0] = __builtin_amdgcn_mfma_f32_16x16x32_bf16(a0, bl0, acc[0][0], 0, 0, 0);
            acc[0][1] = __builtin_amdgcn_mfma_f32_16x16x32_bf16(a0, bl1, acc[0][1], 0, 0, 0);
            acc[1][0] = __builtin_amdgcn_mfma_f32_16x16x32_bf16(a1, bl0, acc[1][0], 0, 0, 0);
            acc[1][1] = __builtin_amdgcn_mfma_f32_16x16x32_bf16(a1, bl1, acc[1][1], 0, 0, 0);
        }
    }

    // ---- hoisted phase-2a: p2 = vh@W_v (independent of vagg and cvec) ----
    int rt = (w & 3) * 16, ct = (w >> 2) * 32;   // wave: 16 rows x 32 cols
    f32x4 p2[2][2];   // [nt][kk]
    #pragma unroll
    for (int nt = 0; nt < 2; ++nt)
        #pragma unroll
        for (int kk = 0; kk < 2; ++kk) p2[nt][kk] = (f32x4){0.f, 0.f, 0.f, 0.f};

    bf16x8 a1h[2], a1l[2];
    #pragma unroll
    for (int kk = 0; kk < 2; ++kk) {
        int d0 = kk * 32 + lhi * 8;
        size_t vo = ((size_t)b * NN + m0 + rt + l16) * 64 + d0;
        a1h[kk] = *(const bf16x8*)(vhHi_in + vo);
        a1l[kk] = *(const bf16x8*)(vhLo_in + vo);
        #pragma unroll
        for (int nt = 0; nt < 2; ++nt) {
            int woff = (ct + nt * 16 + l16) * 64 + d0;
            bf16x8 b1h = *(const bf16x8*)(WvTh + woff);
            bf16x8 b1l = *(const bf16x8*)(WvTl + woff);
            p2[nt][kk] = __builtin_amdgcn_mfma_f32_16x16x32_bf16(a1h[kk], b1h, p2[nt][kk], 0, 0, 0);
            p2[nt][kk] = __builtin_amdgcn_mfma_f32_16x16x32_bf16(a1l[kk], b1h, p2[nt][kk], 0, 0, 0);
            p2[nt][kk] = __builtin_amdgcn_mfma_f32_16x16x32_bf16(a1h[kk], b1l, p2[nt][kk], 0, 0, 0);
        }
    }

    // partial acc -> LDS (per K-half)
    #pragma unroll
    for (int mi = 0; mi < 2; ++mi)
        #pragma unroll
        for (int nt = 0; nt < 2; ++nt)
            #pragma unroll
            for (int r = 0; r < 4; ++r)
                vagg[wk][(wm * 32 + mi * 16 + lhi * 4 + r) * 65 + wn * 32 + nt * 16 + l16] = acc[mi][nt][r];
    __syncthreads();

    // ---- phase 0: color-state update (all 512 threads) ----
    if (t > 0) {
        {
            float s = 0.f;
            #pragma unroll
            for (int j = 0; j < 8; ++j) s += pr[j];
            sRed[tid] = s;
        }
        __syncthreads();
        if (tid < 64) {
            float v = 0.f;
            #pragma unroll
            for (int i = 0; i < 8; ++i) v += sRed[tid + 64 * i];
            sVs[tid] = v;
        }
        __syncthreads();
        {
            float pm = 0.f;
            #pragma unroll
            for (int j = 0; j < 8; ++j) { int k = q * 8 + j; pm += sVs[k] * Wcv[k * 64 + d]; }
            sRed[tid] = pm;
        }
        __syncthreads();
        if (tid < 64) {
            float v = 0.f;
            #pragma unroll
            for (int i = 0; i < 8; ++i) v += sRed[tid + 64 * i];
            sMv[tid] = v;
        }
        __syncthreads();
        float cn[2];
        #pragma unroll
        for (int ci = 0; ci < 2; ++ci) {
            int c = q * 2 + ci;
            float s = sBc[d] + ((c < ncol) ? sMv[d] : 0.f);
            for (int k = 0; k < 64; ++k) s += sChI[c * 64 + k] * sWc[k * 64 + d];
            cn[ci] = fast_tanh(s);
        }
        __syncthreads();
        #pragma unroll
        for (int ci = 0; ci < 2; ++ci) {
            int c = q * 2 + ci;
            sChI[c * 64 + d] = cn[ci];
            if (blkr == 0)
                ch_out[(size_t)b * 1024 + c * 64 + d] = cn[ci];
        }
        __syncthreads();
    }
    {
        float pcs = 0.f;
        #pragma unroll
        for (int ci = 0; ci < 2; ++ci) { int c = q * 2 + ci; if (c < ncol) pcs += sChI[c * 64 + d]; }
        sRed[tid] = pcs;
    }
    __syncthreads();
    if (tid < 64) {
        float v = 0.f;
        #pragma unroll
        for (int i = 0; i < 8; ++i) v += sRed[tid + 64 * i];
        sCs[tid] = v;
    }
    __syncthreads();
    {
        float pv = 0.f;
        #pragma unroll
        for (int j = 0; j < 8; ++j) { int k = q * 8 + j; pv += sCs[k] * Wvc[k * 64 + d]; }
        sRed[tid] = pv;
    }
    __syncthreads();
    if (tid < 64) {
        float v = sBv[tid];
        #pragma unroll
        for (int i = 0; i < 8; ++i) v += sRed[tid + 64 * i];
        sCv[tid] = v;
    }
    __syncthreads();

    // ---- phase 2b: p2 += (v_agg + vh)@W_vv ; + cvec ; tanh ----
    #pragma unroll
    for (int kk = 0; kk < 2; ++kk) {
        int d0 = kk * 32 + lhi * 8;
        int vb = (rt + l16) * 65 + d0;
        bf16x8 a2h, a2l;
        #pragma unroll
        for (int e = 0; e < 8; ++e) {
            float v = vagg[0][vb + e] + vagg[1][vb + e] + (float)a1h[kk][e] + (float)a1l[kk][e];
            bf16 h, l; split2(v, h, l);
            a2h[e] = h; a2l[e] = l;
        }
        #pragma unroll
        for (int nt = 0; nt < 2; ++nt) {
            int woff = (ct + nt * 16 + l16) * 64 + d0;
            bf16x8 b2h = *(const bf16x8*)(WvvTh + woff);
            bf16x8 b2l = *(const bf16x8*)(WvvTl + woff);
            p2[nt][kk] = __builtin_amdgcn_mfma_f32_16x16x32_bf16(a2h, b2h, p2[nt][kk], 0, 0, 0);
            p2[nt][kk] = __builtin_amdgcn_mfma_f32_16x16x32_bf16(a2l, b2h, p2[nt][kk], 0, 0, 0);
            p2[nt][kk] = __builtin_amdgcn_mfma_f32_16x16x32_bf16(a2h, b2l, p2[nt][kk], 0, 0, 0);
        }
    }

    float tvv[2][4];
    #pragma unroll
    for (int nt = 0; nt < 2; ++nt) {
        float cv = sCv[ct + nt * 16 + l16];
        #pragma unroll
        for (int r = 0; r < 4; ++r) tvv[nt][r] = fast_tanh(p2[nt][0][r] + p2[nt][1][r] + cv);
    }

    if (t < TT - 1) {
        int ksW = (m0 + rt) >> 5;
        int khi = 2 * ((rt >> 4) & 1) + (lhi >> 1);
        bf16x4 pkh[2], pkl[2];
        #pragma unroll
        for (int nt = 0; nt < 2; ++nt) {
            int col = ct + nt * 16 + l16;
            float cs = tvv[nt][0] + tvv[nt][1] + tvv[nt][2] + tvv[nt][3];
            cs += __shfl_xor(cs, 16);
            cs += __shfl_xor(cs, 32);
            if (lhi == 0)
                part_out[(((size_t)b * 16 + blkr) * 4 + (w & 3)) * 64 + col] = cs;

            #pragma unroll
            for (int r = 0; r < 4; ++r) {
                bf16 h, l; split2(tvv[nt][r], h, l);
                pkh[nt][r] = h; pkl[nt][r] = l;
            }
            size_t fo = (size_t)b * 65536 + (size_t)ksW * 2048 + col * 32 + khi * 8 + (lhi & 1) * 4;
            *(bf16x4*)(VfHi_out + fo) = pkh[nt];
            *(bf16x4*)(VfLo_out + fo) = pkl[nt];
        }
        // ---- coalesced vh row writes via LDS transpose (reuse vagg) ----
        __syncthreads();   // all vagg reads (phase 2b) complete before overwrite
        bf16* sVhH = (bf16*)&vagg[0][0];       // [64][72]
        bf16* sVhL = sVhH + 64 * 72;
        #pragma unroll
        for (int nt = 0; nt < 2; ++nt) {
            int col = ct + nt * 16 + l16;
            #pragma unroll
            for (int r = 0; r < 4; ++r) {
                sVhH[(rt + lhi * 4 + r) * 72 + col] = pkh[nt][r];
                sVhL[(rt + lhi * 4 + r) * 72 + col] = pkl[nt][r];
            }
        }
        __syncthreads();
        int row = tid >> 3, c8 = (tid & 7) * 8;
        size_t ro = ((size_t)b * NN + m0 + row) * 64 + c8;
        *(bf16x8*)(vhHi_out + ro) = *(bf16x8*)(sVhH + row * 72 + c8);
        *(bf16x8*)(vhLo_out + ro) = *(bf16x8*)(sVhL + row * 72 + c8);
    } else {
        // ---- fused vote MLP: reassemble vh rows in LDS (reuse vagg), then MLP ----
        __syncthreads();   // all vagg reads in phase 2 complete
        float* sX  = &vagg[0][0];     // [64][65] fp32 vh rows
        float* sW1 = &vagg[1][0];     // 1024 fp32
        #pragma unroll
        for (int nt = 0; nt < 2; ++nt) {
            int col = ct + nt * 16 + l16;
            #pragma unroll
            for (int r = 0; r < 4; ++r)
                sX[(rt + lhi * 4 + r) * 65 + col] = tvv[nt][r];
        }
        for (int e = tid; e < 1024; e += 512) sW1[e] = W1[e];
        if (tid < 16) { sVs[tid] = W2[tid]; sMv[tid] = b1[tid]; }
        __syncthreads();

        int nl = tid & 63;          // row within block
        int jq = tid >> 6;          // 8 groups x 2 hidden units
        float h0 = sMv[jq * 2], h1 = sMv[jq * 2 + 1];
        for (int dd = 0; dd < 64; ++dd) {
            float x = sX[nl * 65 + dd];
            h0 += x * sW1[dd * 16 + jq * 2];
            h1 += x * sW1[dd * 16 + jq * 2 + 1];
        }
        float pv = sVs[jq * 2] / (1.f + __expf(-h0)) + sVs[jq * 2 + 1] / (1.f + __expf(-h1));
        sRed[tid] = pv;
        __syncthreads();
        if (tid < 64) {
            float v = 0.f;
            #pragma unroll
            for (int i = 0; i < 8; ++i) v += sRed[tid + 64 * i];
            #pragma unroll
            for (int off = 1; off < 64; off <<= 1) v += __shfl_xor(v, off);
            if (tid == 0) partial[blockIdx.x] = v;
        }
    }
}

// ---------------- final reduce: 16 partials per batch, mean+sigmoid ----------------
__global__ __launch_bounds__(256) void final_reduce_kernel(
    const float* __restrict__ partial, const float* __restrict__ b2, float* __restrict__ out)
{
    int tid = threadIdx.x;
    int b = tid >> 4, p = tid & 15;
    float v = partial[p * 16 + b];
    #pragma unroll
    for (int off = 1; off < 16; off <<= 1) v += __shfl_xor(v, off);
    if (p == 0) out[b] = 1.f / (1.f + expf(-(v / 1024.f + b2[0])));
}

extern "C" void kernel_launch(void* const* d_in, const int* in_sizes, int n_in,
                              void* d_out, int out_size, void* d_ws, size_t ws_size,
                              hipStream_t stream) {
    const float* Mvv  = (const float*)d_in[0];
    const int*   ncol = (const int*)d_in[1];
    const float* vini = (const float*)d_in[2];
    const float* ch0  = (const float*)d_in[3];
    const float* W_v  = (const float*)d_in[4];
    const float* W_vv = (const float*)d_in[5];
    const float* W_vc = (const float*)d_in[6];
    const float* b_v  = (const float*)d_in[7];
    const float* W_c  = (const float*)d_in[8];
    const float* W_cv = (const float*)d_in[9];
    const float* b_c  = (const float*)d_in[10];
    const float* W1   = (const float*)d_in[11];
    const float* b1   = (const float*)d_in[12];
    const float* W2   = (const float*)d_in[13];
    const float* b2   = (const float*)d_in[14];

    char* base = (char*)d_ws;
    size_t off = 0;
    u64* Abits = (u64*)(base + off); off += (size_t)BB * NN * 16 * 8;        // 2 MB
    const size_t SVH = (size_t)BB * NN * DD * 2;                              // 2 MB
    bf16* vhHi[2] = {(bf16*)(base + off), (bf16*)(base + off + SVH)}; off += 2 * SVH;
    bf16* vhLo[2] = {(bf16*)(base + off), (bf16*)(base + off + SVH)}; off += 2 * SVH;
    bf16* VfHi[2] = {(bf16*)(base + off), (bf16*)(base + off + SVH)}; off += 2 * SVH;
    bf16* VfLo[2] = {(bf16*)(base + off), (bf16*)(base + off + SVH)}; off += 2 * SVH;
    const size_t SCH = (size_t)BB * CC * DD * 4;
    float* chb[2] = {(float*)(base + off), (float*)(base + off + SCH)}; off += 2 * SCH;
    const size_t SPB = (size_t)BB * 64 * DD * 4;                              // 256 KB
    float* pb[2] = {(float*)(base + off), (float*)(base + off + SPB)}; off += 2 * SPB;
    bf16* WvTh  = (bf16*)(base + off); off += DD * DD * 2;
    bf16* WvTl  = (bf16*)(base + off); off += DD * DD * 2;
    bf16* WvvTh = (bf16*)(base + off); off += DD * DD * 2;
    bf16* WvvTl = (bf16*)(base + off); off += DD * DD * 2;
    float* partial = (float*)(base + off); off += 256 * 4;

    prep_kernel<<<5121, 256, 0, stream>>>(Mvv, vini, W_v, W_vv, Abits,
        vhHi[0], vhLo[0], VfHi[0], VfLo[0], WvTh, WvTl, WvvTh, WvvTl);

    for (int t = 0; t < TT; ++t) {
        const float* ch_in = (t <= 1) ? ch0 : chb[(t - 1) & 1];
        int i = t & 1, o = (t + 1) & 1;
        step_kernel<<<256, 512, 0, stream>>>(Abits,
            vhHi[i], vhLo[i], VfHi[i], VfLo[i],
            vhHi[o], vhLo[o], VfHi[o], VfLo[o],
            ch_in, chb[t & 1],
            pb[(t + 1) & 1], pb[t & 1],
            ncol, W_c, W_cv, b_c, W_vc, b_v,
            WvTh, WvTl, WvvTh, WvvTl,
            W1, b1, W2, partial, t);
    }

    final_reduce_kernel<<<1, 256, 0, stream>>>(partial, b2, (float*)d_out);
}